// Round 1
// baseline (222.363 us; speedup 1.0000x reference)
//
#include <hip/hip_runtime.h>
#include <hip/hip_bf16.h>
#include <math.h>

#define S_LEN 4096
#define NH 8
#define HD 64
#define QT 64
#define KT 64
#define LDP 72   // padded LDS leading dim in shorts (144 B row: breaks 128 B bank stride)

typedef __attribute__((ext_vector_type(8))) short bf16x8;
typedef __attribute__((ext_vector_type(4))) float f32x4;
typedef __attribute__((ext_vector_type(4))) short short4v;

__device__ __forceinline__ short f2bf(float f) {
    union { float f; unsigned u; } v; v.f = f;
    unsigned r = (v.u + 0x7fffu + ((v.u >> 16) & 1u)) >> 16;  // RNE fp32->bf16
    return (short)r;
}

__global__ __launch_bounds__(256, 4)
void zz_fa_kernel(const float* __restrict__ Q, const float* __restrict__ K,
                  const float* __restrict__ V, float* __restrict__ Out) {
    const int h  = blockIdx.x & 7;
    const int qt = 63 - (blockIdx.x >> 3);   // heavy q-tiles first
    const int qbase = qt * QT;

    const int tid  = threadIdx.x;
    const int wave = tid >> 6;
    const int lane = tid & 63;
    const int l15  = lane & 15;
    const int quad = lane >> 4;

    __shared__ short Kb[KT][LDP];      // K tile [kk][d], bf16
    __shared__ short Vt[HD][LDP];      // V tile transposed [d][kk], bf16
    __shared__ short Pb[4][16][LDP];   // per-wave P tile [row][kk], bf16

    // --- Q fragments in A-layout (m = lane&15, k = quad*8+j), rows wave*16+l15 ---
    const int qrow = qbase + wave * 16 + l15;
    bf16x8 qf[2];
    {
        const float* qp = Q + ((size_t)qrow * NH + h) * HD + quad * 8;
        #pragma unroll
        for (int c = 0; c < 2; ++c) {
            const float* p = qp + c * 32;
            float4 a = *(const float4*)p;
            float4 b = *(const float4*)(p + 4);
            bf16x8 f;
            f[0]=f2bf(a.x); f[1]=f2bf(a.y); f[2]=f2bf(a.z); f[3]=f2bf(a.w);
            f[4]=f2bf(b.x); f[5]=f2bf(b.y); f[6]=f2bf(b.z); f[7]=f2bf(b.w);
            qf[c] = f;
        }
    }

    f32x4 o[4];
    #pragma unroll
    for (int nt = 0; nt < 4; ++nt) o[nt] = (f32x4)0.f;
    float m_i[4] = {-INFINITY, -INFINITY, -INFINITY, -INFINITY};
    float l_i[4] = {0.f, 0.f, 0.f, 0.f};

    // staging assignments
    const int kkK = tid >> 2;           // K: row
    const int dK  = (tid & 3) * 16;     // K: col base (16 floats per thread)
    const int kkV = tid & 63;           // V: row (lane-contiguous -> conflict-free transpose writes)
    const int dV  = (tid >> 6) * 16;    // V: col base

    const float scale = 0.125f;

    for (int kt = 0; kt <= qt; ++kt) {
        const int kbase = kt * KT;
        __syncthreads();   // protect LDS from previous iteration's readers
        // --- stage K -> Kb[kk][d] (bf16) ---
        {
            const float* kp = K + ((size_t)(kbase + kkK) * NH + h) * HD + dK;
            #pragma unroll
            for (int i = 0; i < 4; ++i) {
                float4 x = *(const float4*)(kp + i * 4);
                short4v s4;
                s4[0]=f2bf(x.x); s4[1]=f2bf(x.y); s4[2]=f2bf(x.z); s4[3]=f2bf(x.w);
                *(short4v*)&Kb[kkK][dK + i * 4] = s4;
            }
        }
        // --- stage V transposed -> Vt[d][kk] (bf16) ---
        {
            const float* vp = V + ((size_t)(kbase + kkV) * NH + h) * HD + dV;
            #pragma unroll
            for (int i = 0; i < 4; ++i) {
                float4 x = *(const float4*)(vp + i * 4);
                Vt[dV + i*4 + 0][kkV] = f2bf(x.x);
                Vt[dV + i*4 + 1][kkV] = f2bf(x.y);
                Vt[dV + i*4 + 2][kkV] = f2bf(x.z);
                Vt[dV + i*4 + 3][kkV] = f2bf(x.w);
            }
        }
        __syncthreads();

        // --- S = Q K^T  (per wave: 16 rows x 64 keys) ---
        f32x4 s[4];
        #pragma unroll
        for (int nt = 0; nt < 4; ++nt) {
            f32x4 acc = (f32x4)0.f;
            #pragma unroll
            for (int kc = 0; kc < 2; ++kc) {
                bf16x8 bf = *(const bf16x8*)&Kb[nt*16 + l15][kc*32 + quad*8];
                acc = __builtin_amdgcn_mfma_f32_16x16x32_bf16(qf[kc], bf, acc, 0, 0, 0);
            }
            s[nt] = acc;
        }

        // --- scale + causal mask (diagonal tile only) ---
        if (kt == qt) {
            #pragma unroll
            for (int nt = 0; nt < 4; ++nt) {
                const int kj = nt*16 + l15;
                #pragma unroll
                for (int r = 0; r < 4; ++r) {
                    const int qi = wave*16 + quad*4 + r;
                    s[nt][r] = (kj <= qi) ? s[nt][r] * scale : -INFINITY;
                }
            }
        } else {
            #pragma unroll
            for (int nt = 0; nt < 4; ++nt)
                #pragma unroll
                for (int r = 0; r < 4; ++r) s[nt][r] *= scale;
        }

        // --- row max across 64 keys ---
        float alpha[4], lsum[4];
        #pragma unroll
        for (int r = 0; r < 4; ++r) {
            float mx = fmaxf(fmaxf(s[0][r], s[1][r]), fmaxf(s[2][r], s[3][r]));
            #pragma unroll
            for (int msk = 1; msk < 16; msk <<= 1)
                mx = fmaxf(mx, __shfl_xor(mx, msk));
            const float mnew = fmaxf(m_i[r], mx);
            alpha[r] = __expf(m_i[r] - mnew);   // exp(-inf)=0 on first tile
            m_i[r] = mnew;
            lsum[r] = 0.f;
        }

        // --- P = exp(S - m), write to wave-private LDS tile (C-layout -> A-layout) ---
        #pragma unroll
        for (int nt = 0; nt < 4; ++nt) {
            #pragma unroll
            for (int r = 0; r < 4; ++r) {
                const float p = __expf(s[nt][r] - m_i[r]);
                lsum[r] += p;
                Pb[wave][quad*4 + r][nt*16 + l15] = f2bf(p);
            }
        }
        #pragma unroll
        for (int r = 0; r < 4; ++r) {
            float ls = lsum[r];
            #pragma unroll
            for (int msk = 1; msk < 16; msk <<= 1)
                ls += __shfl_xor(ls, msk);
            l_i[r] = l_i[r] * alpha[r] + ls;
        }

        // --- O = O*alpha + P V ---
        #pragma unroll
        for (int nt = 0; nt < 4; ++nt)
            #pragma unroll
            for (int r = 0; r < 4; ++r)
                o[nt][r] *= alpha[r];

        bf16x8 pf[2];
        #pragma unroll
        for (int kc = 0; kc < 2; ++kc)
            pf[kc] = *(const bf16x8*)&Pb[wave][l15][kc*32 + quad*8];
        #pragma unroll
        for (int nt = 0; nt < 4; ++nt) {
            #pragma unroll
            for (int kc = 0; kc < 2; ++kc) {
                bf16x8 vf = *(const bf16x8*)&Vt[nt*16 + l15][kc*32 + quad*8];
                o[nt] = __builtin_amdgcn_mfma_f32_16x16x32_bf16(pf[kc], vf, o[nt], 0, 0, 0);
            }
        }
    }

    // --- epilogue: normalize, zigzag-permuted writes of out and lse ---
    #pragma unroll
    for (int r = 0; r < 4; ++r) {
        const int qi   = qbase + wave*16 + quad*4 + r;
        const int g    = qi >> 9;                    // global chunk (C=512)
        const int rank = (g < 4) ? g : (7 - g);
        const int pos  = ((g < 4) ? 0 : 512) + (qi & 511);
        const float inv = 1.f / l_i[r];
        float* ob = Out + ((size_t)(rank * 1024 + pos) * NH + h) * HD;
        #pragma unroll
        for (int nt = 0; nt < 4; ++nt)
            ob[nt*16 + l15] = o[nt][r] * inv;
        if (l15 == 0)
            Out[2097152 + (rank*8 + h)*1024 + pos] = m_i[r] + __logf(l_i[r]);
    }
}

extern "C" void kernel_launch(void* const* d_in, const int* in_sizes, int n_in,
                              void* d_out, int out_size, void* d_ws, size_t ws_size,
                              hipStream_t stream) {
    const float* q = (const float*)d_in[0];
    const float* k = (const float*)d_in[1];
    const float* v = (const float*)d_in[2];
    float* out = (float*)d_out;
    zz_fa_kernel<<<dim3(512), dim3(256), 0, stream>>>(q, k, v, out);
}

// Round 2
// 179.677 us; speedup vs baseline: 1.2376x; 1.2376x over previous
//
#include <hip/hip_runtime.h>
#include <hip/hip_bf16.h>
#include <math.h>

#define S_LEN 4096
#define NH 8
#define HD 64
#define QT 64
#define KT 64
#define LDP 72   // padded LDS leading dim in shorts (144 B row: breaks 128 B bank stride)
#define MAXC 4   // max K-chunks per q-tile (chunk = 16 k-tiles = 1024 keys)

typedef __attribute__((ext_vector_type(8))) short bf16x8;
typedef __attribute__((ext_vector_type(4))) float f32x4;
typedef __attribute__((ext_vector_type(4))) short short4v;

__device__ __forceinline__ short f2bf(float f) {
    union { float f; unsigned u; } v; v.f = f;
    unsigned r = (v.u + 0x7fffu + ((v.u >> 16) & 1u)) >> 16;  // RNE fp32->bf16
    return (short)r;
}

// ---------------- split-K flash attention: one block = (head, q-tile, k-chunk) ----------------
__global__ __launch_bounds__(256, 4)
void zz_fa_split(const float* __restrict__ Q, const float* __restrict__ K,
                 const float* __restrict__ V, float* __restrict__ Po,
                 float* __restrict__ Ml) {
    const int h = blockIdx.x & 7;
    const int t = 159 - (blockIdx.x >> 3);   // heavy chunks (big qt) first
    int qt, c;
    if (t < 16)      { qt = t;               c = 0; }
    else if (t < 48) { qt = 16 + (t-16)/2;   c = (t-16)%2; }
    else if (t < 96) { qt = 32 + (t-48)/3;   c = (t-48)%3; }
    else             { qt = 48 + (t-96)/4;   c = (t-96)%4; }
    const int k0 = c * 16;
    const int k1 = min(k0 + 16, qt + 1);
    const int qbase = qt * QT;

    const int tid  = threadIdx.x;
    const int wave = tid >> 6;
    const int lane = tid & 63;
    const int l15  = lane & 15;
    const int quad = lane >> 4;

    __shared__ short Kb[KT][LDP];      // K tile [kk][d], bf16
    __shared__ short Vt[HD][LDP];      // V tile transposed [d][kk], bf16
    __shared__ short Pb[4][16][LDP];   // per-wave P tile [row][kk], bf16

    // --- Q fragments in A-layout (m = lane&15, k = quad*8+j), rows wave*16+l15 ---
    const int qrow = qbase + wave * 16 + l15;
    bf16x8 qf[2];
    {
        const float* qp = Q + ((size_t)qrow * NH + h) * HD + quad * 8;
        #pragma unroll
        for (int cc = 0; cc < 2; ++cc) {
            const float* p = qp + cc * 32;
            float4 a = *(const float4*)p;
            float4 b = *(const float4*)(p + 4);
            bf16x8 f;
            f[0]=f2bf(a.x); f[1]=f2bf(a.y); f[2]=f2bf(a.z); f[3]=f2bf(a.w);
            f[4]=f2bf(b.x); f[5]=f2bf(b.y); f[6]=f2bf(b.z); f[7]=f2bf(b.w);
            qf[cc] = f;
        }
    }

    f32x4 o[4];
    #pragma unroll
    for (int nt = 0; nt < 4; ++nt) o[nt] = (f32x4)0.f;
    float m_i[4] = {-INFINITY, -INFINITY, -INFINITY, -INFINITY};
    float l_i[4] = {0.f, 0.f, 0.f, 0.f};

    // staging assignments
    const int kkK = tid >> 2;           // K: row
    const int dK  = (tid & 3) * 16;     // K: col base
    const int kkV = tid & 63;           // V: row
    const int dV  = (tid >> 6) * 16;    // V: col base

    const float scale = 0.125f;

    for (int kt = k0; kt < k1; ++kt) {
        const int kbase = kt * KT;
        __syncthreads();
        {
            const float* kp = K + ((size_t)(kbase + kkK) * NH + h) * HD + dK;
            #pragma unroll
            for (int i = 0; i < 4; ++i) {
                float4 x = *(const float4*)(kp + i * 4);
                short4v s4;
                s4[0]=f2bf(x.x); s4[1]=f2bf(x.y); s4[2]=f2bf(x.z); s4[3]=f2bf(x.w);
                *(short4v*)&Kb[kkK][dK + i * 4] = s4;
            }
        }
        {
            const float* vp = V + ((size_t)(kbase + kkV) * NH + h) * HD + dV;
            #pragma unroll
            for (int i = 0; i < 4; ++i) {
                float4 x = *(const float4*)(vp + i * 4);
                Vt[dV + i*4 + 0][kkV] = f2bf(x.x);
                Vt[dV + i*4 + 1][kkV] = f2bf(x.y);
                Vt[dV + i*4 + 2][kkV] = f2bf(x.z);
                Vt[dV + i*4 + 3][kkV] = f2bf(x.w);
            }
        }
        __syncthreads();

        // --- S = Q K^T ---
        f32x4 s[4];
        #pragma unroll
        for (int nt = 0; nt < 4; ++nt) {
            f32x4 acc = (f32x4)0.f;
            #pragma unroll
            for (int kc = 0; kc < 2; ++kc) {
                bf16x8 bf = *(const bf16x8*)&Kb[nt*16 + l15][kc*32 + quad*8];
                acc = __builtin_amdgcn_mfma_f32_16x16x32_bf16(qf[kc], bf, acc, 0, 0, 0);
            }
            s[nt] = acc;
        }

        // --- scale + causal mask (diagonal tile only) ---
        if (kt == qt) {
            #pragma unroll
            for (int nt = 0; nt < 4; ++nt) {
                const int kj = nt*16 + l15;
                #pragma unroll
                for (int r = 0; r < 4; ++r) {
                    const int qi = wave*16 + quad*4 + r;
                    s[nt][r] = (kj <= qi) ? s[nt][r] * scale : -INFINITY;
                }
            }
        } else {
            #pragma unroll
            for (int nt = 0; nt < 4; ++nt)
                #pragma unroll
                for (int r = 0; r < 4; ++r) s[nt][r] *= scale;
        }

        // --- row max ---
        float alpha[4], lsum[4];
        #pragma unroll
        for (int r = 0; r < 4; ++r) {
            float mx = fmaxf(fmaxf(s[0][r], s[1][r]), fmaxf(s[2][r], s[3][r]));
            #pragma unroll
            for (int msk = 1; msk < 16; msk <<= 1)
                mx = fmaxf(mx, __shfl_xor(mx, msk));
            const float mnew = fmaxf(m_i[r], mx);
            alpha[r] = __expf(m_i[r] - mnew);
            m_i[r] = mnew;
            lsum[r] = 0.f;
        }

        // --- P = exp(S-m) -> wave-private LDS (C-layout -> A-layout) ---
        #pragma unroll
        for (int nt = 0; nt < 4; ++nt) {
            #pragma unroll
            for (int r = 0; r < 4; ++r) {
                const float p = __expf(s[nt][r] - m_i[r]);
                lsum[r] += p;
                Pb[wave][quad*4 + r][nt*16 + l15] = f2bf(p);
            }
        }
        #pragma unroll
        for (int r = 0; r < 4; ++r) {
            float ls = lsum[r];
            #pragma unroll
            for (int msk = 1; msk < 16; msk <<= 1)
                ls += __shfl_xor(ls, msk);
            l_i[r] = l_i[r] * alpha[r] + ls;
        }

        // --- O = O*alpha + P V ---
        #pragma unroll
        for (int nt = 0; nt < 4; ++nt)
            #pragma unroll
            for (int r = 0; r < 4; ++r)
                o[nt][r] *= alpha[r];

        bf16x8 pf[2];
        #pragma unroll
        for (int kc = 0; kc < 2; ++kc)
            pf[kc] = *(const bf16x8*)&Pb[wave][l15][kc*32 + quad*8];
        #pragma unroll
        for (int nt = 0; nt < 4; ++nt) {
            #pragma unroll
            for (int kc = 0; kc < 2; ++kc) {
                bf16x8 vf = *(const bf16x8*)&Vt[nt*16 + l15][kc*32 + quad*8];
                o[nt] = __builtin_amdgcn_mfma_f32_16x16x32_bf16(pf[kc], vf, o[nt], 0, 0, 0);
            }
        }
    }

    // --- epilogue: write UNNORMALIZED partials + (m,l) to workspace ---
    #pragma unroll
    for (int r = 0; r < 4; ++r) {
        const int qi = qbase + wave*16 + quad*4 + r;
        float* pb = Po + (((size_t)(h * MAXC + c) * S_LEN) + qi) * HD;
        #pragma unroll
        for (int nt = 0; nt < 4; ++nt)
            pb[nt*16 + l15] = o[nt][r];
        if (l15 == 0) {
            Ml[(((size_t)(h * MAXC + c) * S_LEN) + qi) * 2 + 0] = m_i[r];
            Ml[(((size_t)(h * MAXC + c) * S_LEN) + qi) * 2 + 1] = l_i[r];
        }
    }
}

// ---------------- merge: combine <=4 chunks per (h,qrow), zigzag-permute, lse ----------------
__global__ __launch_bounds__(256, 4)
void zz_merge(const float* __restrict__ Po, const float* __restrict__ Ml,
              float* __restrict__ Out) {
    const int idx  = blockIdx.x * 256 + threadIdx.x;  // [h][qrow][d]
    const int d    = idx & 63;
    const int qrow = (idx >> 6) & 4095;
    const int h    = idx >> 18;
    const int qt   = qrow >> 6;
    const int nc   = (qt >> 4) + 1;   // wave-uniform (qt constant across 64-row span)

    float m = -INFINITY;
    #pragma unroll 4
    for (int c = 0; c < nc; ++c)
        m = fmaxf(m, Ml[(((size_t)(h*MAXC + c) * S_LEN) + qrow)*2 + 0]);

    float L = 0.f, acc = 0.f;
    #pragma unroll 4
    for (int c = 0; c < nc; ++c) {
        const size_t b = ((size_t)(h*MAXC + c) * S_LEN) + qrow;
        const float w = __expf(Ml[b*2 + 0] - m);
        L   += Ml[b*2 + 1] * w;
        acc += Po[b * HD + d] * w;
    }

    const int g    = qrow >> 9;
    const int rank = (g < 4) ? g : (7 - g);
    const int pos  = ((g < 4) ? 0 : 512) + (qrow & 511);
    Out[((size_t)(rank * 1024 + pos) * NH + h) * HD + d] = acc / L;
    if (d == 0)
        Out[2097152 + (rank*8 + h)*1024 + pos] = m + __logf(L);
}

// ---------------- fallback (R1 kernel) if ws too small ----------------
__global__ __launch_bounds__(256, 4)
void zz_fa_mono(const float* __restrict__ Q, const float* __restrict__ K,
                const float* __restrict__ V, float* __restrict__ Out) {
    const int h  = blockIdx.x & 7;
    const int qt = 63 - (blockIdx.x >> 3);
    const int qbase = qt * QT;
    const int tid  = threadIdx.x;
    const int wave = tid >> 6;
    const int lane = tid & 63;
    const int l15  = lane & 15;
    const int quad = lane >> 4;

    __shared__ short Kb[KT][LDP];
    __shared__ short Vt[HD][LDP];
    __shared__ short Pb[4][16][LDP];

    const int qrow = qbase + wave * 16 + l15;
    bf16x8 qf[2];
    {
        const float* qp = Q + ((size_t)qrow * NH + h) * HD + quad * 8;
        #pragma unroll
        for (int cc = 0; cc < 2; ++cc) {
            const float* p = qp + cc * 32;
            float4 a = *(const float4*)p;
            float4 b = *(const float4*)(p + 4);
            bf16x8 f;
            f[0]=f2bf(a.x); f[1]=f2bf(a.y); f[2]=f2bf(a.z); f[3]=f2bf(a.w);
            f[4]=f2bf(b.x); f[5]=f2bf(b.y); f[6]=f2bf(b.z); f[7]=f2bf(b.w);
            qf[cc] = f;
        }
    }
    f32x4 o[4];
    #pragma unroll
    for (int nt = 0; nt < 4; ++nt) o[nt] = (f32x4)0.f;
    float m_i[4] = {-INFINITY, -INFINITY, -INFINITY, -INFINITY};
    float l_i[4] = {0.f, 0.f, 0.f, 0.f};
    const int kkK = tid >> 2, dK = (tid & 3) * 16;
    const int kkV = tid & 63, dV = (tid >> 6) * 16;
    const float scale = 0.125f;

    for (int kt = 0; kt <= qt; ++kt) {
        const int kbase = kt * KT;
        __syncthreads();
        {
            const float* kp = K + ((size_t)(kbase + kkK) * NH + h) * HD + dK;
            #pragma unroll
            for (int i = 0; i < 4; ++i) {
                float4 x = *(const float4*)(kp + i * 4);
                short4v s4;
                s4[0]=f2bf(x.x); s4[1]=f2bf(x.y); s4[2]=f2bf(x.z); s4[3]=f2bf(x.w);
                *(short4v*)&Kb[kkK][dK + i * 4] = s4;
            }
        }
        {
            const float* vp = V + ((size_t)(kbase + kkV) * NH + h) * HD + dV;
            #pragma unroll
            for (int i = 0; i < 4; ++i) {
                float4 x = *(const float4*)(vp + i * 4);
                Vt[dV + i*4 + 0][kkV] = f2bf(x.x);
                Vt[dV + i*4 + 1][kkV] = f2bf(x.y);
                Vt[dV + i*4 + 2][kkV] = f2bf(x.z);
                Vt[dV + i*4 + 3][kkV] = f2bf(x.w);
            }
        }
        __syncthreads();
        f32x4 s[4];
        #pragma unroll
        for (int nt = 0; nt < 4; ++nt) {
            f32x4 acc = (f32x4)0.f;
            #pragma unroll
            for (int kc = 0; kc < 2; ++kc) {
                bf16x8 bf = *(const bf16x8*)&Kb[nt*16 + l15][kc*32 + quad*8];
                acc = __builtin_amdgcn_mfma_f32_16x16x32_bf16(qf[kc], bf, acc, 0, 0, 0);
            }
            s[nt] = acc;
        }
        if (kt == qt) {
            #pragma unroll
            for (int nt = 0; nt < 4; ++nt) {
                const int kj = nt*16 + l15;
                #pragma unroll
                for (int r = 0; r < 4; ++r) {
                    const int qi = wave*16 + quad*4 + r;
                    s[nt][r] = (kj <= qi) ? s[nt][r] * scale : -INFINITY;
                }
            }
        } else {
            #pragma unroll
            for (int nt = 0; nt < 4; ++nt)
                #pragma unroll
                for (int r = 0; r < 4; ++r) s[nt][r] *= scale;
        }
        float alpha[4], lsum[4];
        #pragma unroll
        for (int r = 0; r < 4; ++r) {
            float mx = fmaxf(fmaxf(s[0][r], s[1][r]), fmaxf(s[2][r], s[3][r]));
            #pragma unroll
            for (int msk = 1; msk < 16; msk <<= 1)
                mx = fmaxf(mx, __shfl_xor(mx, msk));
            const float mnew = fmaxf(m_i[r], mx);
            alpha[r] = __expf(m_i[r] - mnew);
            m_i[r] = mnew;
            lsum[r] = 0.f;
        }
        #pragma unroll
        for (int nt = 0; nt < 4; ++nt) {
            #pragma unroll
            for (int r = 0; r < 4; ++r) {
                const float p = __expf(s[nt][r] - m_i[r]);
                lsum[r] += p;
                Pb[wave][quad*4 + r][nt*16 + l15] = f2bf(p);
            }
        }
        #pragma unroll
        for (int r = 0; r < 4; ++r) {
            float ls = lsum[r];
            #pragma unroll
            for (int msk = 1; msk < 16; msk <<= 1)
                ls += __shfl_xor(ls, msk);
            l_i[r] = l_i[r] * alpha[r] + ls;
        }
        #pragma unroll
        for (int nt = 0; nt < 4; ++nt)
            #pragma unroll
            for (int r = 0; r < 4; ++r)
                o[nt][r] *= alpha[r];
        bf16x8 pf[2];
        #pragma unroll
        for (int kc = 0; kc < 2; ++kc)
            pf[kc] = *(const bf16x8*)&Pb[wave][l15][kc*32 + quad*8];
        #pragma unroll
        for (int nt = 0; nt < 4; ++nt) {
            #pragma unroll
            for (int kc = 0; kc < 2; ++kc) {
                bf16x8 vf = *(const bf16x8*)&Vt[nt*16 + l15][kc*32 + quad*8];
                o[nt] = __builtin_amdgcn_mfma_f32_16x16x32_bf16(pf[kc], vf, o[nt], 0, 0, 0);
            }
        }
    }
    #pragma unroll
    for (int r = 0; r < 4; ++r) {
        const int qi   = qbase + wave*16 + quad*4 + r;
        const int g    = qi >> 9;
        const int rank = (g < 4) ? g : (7 - g);
        const int pos  = ((g < 4) ? 0 : 512) + (qi & 511);
        const float inv = 1.f / l_i[r];
        float* ob = Out + ((size_t)(rank * 1024 + pos) * NH + h) * HD;
        #pragma unroll
        for (int nt = 0; nt < 4; ++nt)
            ob[nt*16 + l15] = o[nt][r] * inv;
        if (l15 == 0)
            Out[2097152 + (rank*8 + h)*1024 + pos] = m_i[r] + __logf(l_i[r]);
    }
}

extern "C" void kernel_launch(void* const* d_in, const int* in_sizes, int n_in,
                              void* d_out, int out_size, void* d_ws, size_t ws_size,
                              hipStream_t stream) {
    const float* q = (const float*)d_in[0];
    const float* k = (const float*)d_in[1];
    const float* v = (const float*)d_in[2];
    float* out = (float*)d_out;

    const size_t po_elems = (size_t)NH * MAXC * S_LEN * HD;   // 8.39M floats
    const size_t ml_elems = (size_t)NH * MAXC * S_LEN * 2;    // 262K floats
    const size_t need = (po_elems + ml_elems) * sizeof(float); // ~34.6 MB

    if (ws_size >= need) {
        float* Po = (float*)d_ws;
        float* Ml = Po + po_elems;
        zz_fa_split<<<dim3(1280), dim3(256), 0, stream>>>(q, k, v, Po, Ml);
        zz_merge<<<dim3((NH * S_LEN * HD) / 256), dim3(256), 0, stream>>>(Po, Ml, out);
    } else {
        zz_fa_mono<<<dim3(512), dim3(256), 0, stream>>>(q, k, v, out);
    }
}

// Round 3
// 131.471 us; speedup vs baseline: 1.6913x; 1.3667x over previous
//
#include <hip/hip_runtime.h>
#include <hip/hip_bf16.h>
#include <math.h>
#include <stdint.h>

#define S_LEN 4096
#define NH 8
#define HD 64
#define NKT 64     // 64-key tiles per sequence
#define MAXC 4     // max K-chunks per q-tile (chunk = 16 k-tiles = 1024 keys)

typedef __attribute__((ext_vector_type(8))) short bf16x8;
typedef __attribute__((ext_vector_type(4))) short short4v;
typedef __attribute__((ext_vector_type(4))) float f32x4;

__device__ __forceinline__ short f2bf(float f) {
    union { float f; unsigned u; } v; v.f = f;
    unsigned r = (v.u + 0x7fffu + ((v.u >> 16) & 1u)) >> 16;  // RNE fp32->bf16
    return (short)r;
}
__device__ __forceinline__ float bf2f(unsigned short u) {
    union { unsigned u; float f; } v; v.u = ((unsigned)u) << 16;
    return v.f;
}

// ---- 16x16x16 bf16 MFMA (P-in-register PV): prefer the long-standing _1k name ----
#if __has_builtin(__builtin_amdgcn_mfma_f32_16x16x16bf16_1k)
__device__ __forceinline__ f32x4 mfma16(short4v a, short4v b, f32x4 c) {
    return __builtin_amdgcn_mfma_f32_16x16x16bf16_1k(a, b, c, 0, 0, 0);
}
#elif __has_builtin(__builtin_amdgcn_mfma_f32_16x16x16_bf16)
__device__ __forceinline__ f32x4 mfma16(short4v a, short4v b, f32x4 c) {
    return __builtin_amdgcn_mfma_f32_16x16x16_bf16(a, b, c, 0, 0, 0);
}
#else
// emulate with zero-padded K=32 (consistent k-index on both operands)
__device__ __forceinline__ f32x4 mfma16(short4v a, short4v b, f32x4 c) {
    bf16x8 a8 = {a[0],a[1],a[2],a[3],0,0,0,0};
    bf16x8 b8 = {b[0],b[1],b[2],b[3],0,0,0,0};
    return __builtin_amdgcn_mfma_f32_16x16x32_bf16(a8, b8, c, 0, 0, 0);
}
#endif

// ---- async global->LDS, 16 B per lane ----
__device__ __forceinline__ void gll16(const void* g, void* l) {
#if __has_builtin(__builtin_amdgcn_global_load_lds)
    __builtin_amdgcn_global_load_lds(
        (const __attribute__((address_space(1))) unsigned int*)(uintptr_t)g,
        (__attribute__((address_space(3))) unsigned int*)(unsigned int)(uintptr_t)l,
        16, 0, 0);
#else
    *(bf16x8*)l = *(const bf16x8*)g;
#endif
}

// ================= pre-pass: fp32 K,V -> bf16 K[h][kt][kk][d], Vt[h][kt][d][kk] ==========
__global__ __launch_bounds__(256)
void zz_prep(const float* __restrict__ K, const float* __restrict__ V,
             short* __restrict__ Kbf, short* __restrict__ Vtbf) {
    const int h = blockIdx.x & 7, kt = blockIdx.x >> 3;
    const int tid = threadIdx.x;
    const int r = tid >> 2, c0 = (tid & 3) * 16;
    __shared__ short Vl[64][72];

    const float* kp = K + ((size_t)(kt * 64 + r) * NH + h) * HD + c0;
    const float* vp = V + ((size_t)(kt * 64 + r) * NH + h) * HD + c0;
    bf16x8 kv0, kv1;
    #pragma unroll
    for (int i = 0; i < 8; i += 4) {
        float4 x = *(const float4*)(kp + i);
        kv0[i+0] = f2bf(x.x); kv0[i+1] = f2bf(x.y); kv0[i+2] = f2bf(x.z); kv0[i+3] = f2bf(x.w);
        float4 x2 = *(const float4*)(kp + 8 + i);
        kv1[i+0] = f2bf(x2.x); kv1[i+1] = f2bf(x2.y); kv1[i+2] = f2bf(x2.z); kv1[i+3] = f2bf(x2.w);
        float4 y = *(const float4*)(vp + i);
        Vl[r][c0+i+0] = f2bf(y.x); Vl[r][c0+i+1] = f2bf(y.y);
        Vl[r][c0+i+2] = f2bf(y.z); Vl[r][c0+i+3] = f2bf(y.w);
        float4 y2 = *(const float4*)(vp + 8 + i);
        Vl[r][c0+8+i+0] = f2bf(y2.x); Vl[r][c0+8+i+1] = f2bf(y2.y);
        Vl[r][c0+8+i+2] = f2bf(y2.z); Vl[r][c0+8+i+3] = f2bf(y2.w);
    }
    short* kout = Kbf + ((size_t)(h * NKT + kt) * 64 + r) * 64 + c0;
    *(bf16x8*)kout = kv0;
    *(bf16x8*)(kout + 8) = kv1;
    __syncthreads();
    bf16x8 tv0, tv1;
    #pragma unroll
    for (int i = 0; i < 8; ++i) { tv0[i] = Vl[c0 + i][r]; tv1[i] = Vl[c0 + 8 + i][r]; }
    short* vout = Vtbf + ((size_t)(h * NKT + kt) * 64 + r) * 64 + c0;
    *(bf16x8*)vout = tv0;
    *(bf16x8*)(vout + 8) = tv1;
}

// ================= split-K flash attention main kernel ==========
// wave w owns keys [w*16, w*16+16) of each 64-key tile, all 64 q-rows of the block.
__global__ __launch_bounds__(256, 3)
void zz_fa_split(const float* __restrict__ Q, const short* __restrict__ Kbf,
                 const short* __restrict__ Vtbf, unsigned short* __restrict__ Po,
                 float* __restrict__ Ml) {
    const int h = blockIdx.x & 7;
    const int t = 159 - (blockIdx.x >> 3);   // heavy chunks first
    int qt, c;
    if (t < 16)      { qt = t;               c = 0; }
    else if (t < 48) { qt = 16 + (t-16)/2;   c = (t-16)%2; }
    else if (t < 96) { qt = 32 + (t-48)/3;   c = (t-48)%3; }
    else             { qt = 48 + (t-96)/4;   c = (t-96)%4; }
    const int k0 = c * 16;
    const int k1 = min(k0 + 16, qt + 1);
    const int qbase = qt * 64;

    const int tid  = threadIdx.x;
    const int wave = tid >> 6;
    const int lane = tid & 63;
    const int l15  = lane & 15;
    const int quad = lane >> 4;

    __shared__ __align__(16) char smem[37888];
    short* Kb  = (short*)smem;            // 8 KB staged K tile (swizzled 16B blocks)
    short* Vt  = (short*)(smem + 8192);   // 8 KB staged V^T tile
    float* ObA = (float*)smem;            // epilogue: O reduce buf A [64][66]
    float* ObB = (float*)(smem + 16896);  // epilogue: O reduce buf B
    float* Lb  = (float*)(smem + 33792);  // epilogue: l partials [4][4][64]

    // ---- Q fragments (B-operand layout), scale folded in: qf[nt][kc] ----
    bf16x8 qf[4][2];
    #pragma unroll
    for (int nt = 0; nt < 4; ++nt) {
        #pragma unroll
        for (int kc = 0; kc < 2; ++kc) {
            const float* qp = Q + ((size_t)(qbase + nt*16 + l15) * NH + h) * HD + kc*32 + quad*8;
            float4 a = *(const float4*)qp;
            float4 b = *(const float4*)(qp + 4);
            bf16x8 f;
            f[0]=f2bf(a.x*0.125f); f[1]=f2bf(a.y*0.125f); f[2]=f2bf(a.z*0.125f); f[3]=f2bf(a.w*0.125f);
            f[4]=f2bf(b.x*0.125f); f[5]=f2bf(b.y*0.125f); f[6]=f2bf(b.z*0.125f); f[7]=f2bf(b.w*0.125f);
            qf[nt][kc] = f;
        }
    }

    f32x4 o[4][4];          // O^T accumulator: [dt][nt], d=dt*16+quad*4+r, q=nt*16+l15
    #pragma unroll
    for (int dt = 0; dt < 4; ++dt)
        #pragma unroll
        for (int nt = 0; nt < 4; ++nt) o[dt][nt] = (f32x4)0.f;
    float lloc[4] = {0.f, 0.f, 0.f, 0.f};   // per-lane l partial per q-subtile

    const short* Ktiles = Kbf  + (size_t)h * NKT * 4096;
    const short* Vtiles = Vtbf + (size_t)h * NKT * 4096;

    for (int kt = k0; kt < k1; ++kt) {
        __syncthreads();
        const char* kg = (const char*)(Ktiles + (size_t)kt * 4096);
        const char* vg = (const char*)(Vtiles + (size_t)kt * 4096);
        #pragma unroll
        for (int i = 0; i < 2; ++i) {
            const int lo = i*4096 + tid*16;
            const int row = lo >> 7, blk = ((lo >> 4) & 7) ^ (row & 7);
            gll16(kg + row*128 + blk*16, (char*)Kb + lo);
        }
        #pragma unroll
        for (int i = 0; i < 2; ++i) {
            const int lo = i*4096 + tid*16;
            const int row = lo >> 7, blk = ((lo >> 4) & 7) ^ (row & 7);
            gll16(vg + row*128 + blk*16, (char*)Vt + lo);
        }
        __syncthreads();

        // K fragments (A-operand of S^T): wave's 16 keys, m = l15
        bf16x8 kf[2];
        #pragma unroll
        for (int kc = 0; kc < 2; ++kc) {
            const int row = wave*16 + l15;
            const int blk = (kc*4 + quad) ^ (l15 & 7);
            kf[kc] = *(const bf16x8*)&Kb[row*64 + blk*8];
        }

        // S^T = K·Q^T, then p = exp(s) in-register (C rows == PV B-operand k)
        short4v pfr[4];
        #pragma unroll
        for (int nt = 0; nt < 4; ++nt) {
            f32x4 acc = (f32x4)0.f;
            acc = __builtin_amdgcn_mfma_f32_16x16x32_bf16(kf[0], qf[nt][0], acc, 0, 0, 0);
            acc = __builtin_amdgcn_mfma_f32_16x16x32_bf16(kf[1], qf[nt][1], acc, 0, 0, 0);
            short4v pf;
            if (kt == qt) {   // diagonal tile: causal mask
                #pragma unroll
                for (int r = 0; r < 4; ++r) {
                    const int key  = kt*64 + wave*16 + quad*4 + r;
                    const int qrow = qbase + nt*16 + l15;
                    const float p = (key <= qrow) ? __expf(acc[r]) : 0.f;
                    lloc[nt] += p;
                    pf[r] = f2bf(p);
                }
            } else {
                #pragma unroll
                for (int r = 0; r < 4; ++r) {
                    const float p = __expf(acc[r]);
                    lloc[nt] += p;
                    pf[r] = f2bf(p);
                }
            }
            pfr[nt] = pf;
        }

        // O^T += V^T · P^T  (16x16x16; B = p regs, same lane/regs)
        #pragma unroll
        for (int dt = 0; dt < 4; ++dt) {
            const int row = dt*16 + l15;
            const int blk = (wave*2 + (quad >> 1)) ^ (l15 & 7);
            short4v vf = *(const short4v*)&Vt[row*64 + blk*8 + (quad & 1)*4];
            #pragma unroll
            for (int nt = 0; nt < 4; ++nt)
                o[dt][nt] = mfma16(vf, pfr[nt], o[dt][nt]);
        }
    }

    // ---- epilogue: cross-wave O + l reduction, store bf16 partials ----
    __syncthreads();   // staging LDS now reusable
    #pragma unroll
    for (int nt = 0; nt < 4; ++nt)
        Lb[(wave*4 + quad)*64 + nt*16 + l15] = lloc[nt];
    if (wave == 1 || wave == 3) {
        float* Ob = (wave == 1) ? ObA : ObB;
        #pragma unroll
        for (int dt = 0; dt < 4; ++dt)
            #pragma unroll
            for (int nt = 0; nt < 4; ++nt)
                #pragma unroll
                for (int r = 0; r < 4; ++r)
                    Ob[(dt*16 + quad*4 + r)*66 + nt*16 + l15] = o[dt][nt][r];
    }
    __syncthreads();
    float Lfin = 0.f;
    if (wave == 0) {
        #pragma unroll
        for (int i = 0; i < 16; ++i) Lfin += Lb[i*64 + lane];
        #pragma unroll
        for (int dt = 0; dt < 4; ++dt)
            #pragma unroll
            for (int nt = 0; nt < 4; ++nt)
                #pragma unroll
                for (int r = 0; r < 4; ++r)
                    o[dt][nt][r] += ObA[(dt*16 + quad*4 + r)*66 + nt*16 + l15];
    }
    if (wave == 2) {
        #pragma unroll
        for (int dt = 0; dt < 4; ++dt)
            #pragma unroll
            for (int nt = 0; nt < 4; ++nt)
                #pragma unroll
                for (int r = 0; r < 4; ++r)
                    o[dt][nt][r] += ObB[(dt*16 + quad*4 + r)*66 + nt*16 + l15];
    }
    __syncthreads();
    if (wave == 2) {
        #pragma unroll
        for (int dt = 0; dt < 4; ++dt)
            #pragma unroll
            for (int nt = 0; nt < 4; ++nt)
                #pragma unroll
                for (int r = 0; r < 4; ++r)
                    ObA[(dt*16 + quad*4 + r)*66 + nt*16 + l15] = o[dt][nt][r];
    }
    __syncthreads();
    if (wave == 0) {
        const size_t base = (size_t)(h*MAXC + c) * S_LEN;
        #pragma unroll
        for (int dt = 0; dt < 4; ++dt) {
            #pragma unroll
            for (int nt = 0; nt < 4; ++nt) {
                short4v pk;
                #pragma unroll
                for (int r = 0; r < 4; ++r) {
                    const float v = o[dt][nt][r] + ObA[(dt*16 + quad*4 + r)*66 + nt*16 + l15];
                    pk[r] = f2bf(v);
                }
                *(short4v*)&Po[(base + qbase + nt*16 + l15)*64 + dt*16 + quad*4] = pk;
            }
        }
        Ml[base + qbase + lane] = Lfin;
    }
}

// ================= merge: sum <=4 chunk partials, normalize, zigzag, lse ==========
__global__ __launch_bounds__(256)
void zz_merge(const unsigned short* __restrict__ Po, const float* __restrict__ Ml,
              float* __restrict__ Out) {
    const int idx  = blockIdx.x * 256 + threadIdx.x;  // [h][qrow][d]
    const int d    = idx & 63;
    const int qrow = (idx >> 6) & 4095;
    const int h    = idx >> 18;
    const int nc   = (qrow >> 10) + 1;

    float L = 0.f, O = 0.f;
    #pragma unroll 4
    for (int c = 0; c < nc; ++c) {
        const size_t b = (size_t)(h*MAXC + c) * S_LEN + qrow;
        L += Ml[b];
        O += bf2f(Po[b*64 + d]);
    }
    const int g    = qrow >> 9;
    const int rank = (g < 4) ? g : (7 - g);
    const int pos  = ((g < 4) ? 0 : 512) + (qrow & 511);
    Out[((size_t)(rank*1024 + pos)*NH + h)*HD + d] = O / L;
    if (d == 0)
        Out[2097152 + (rank*8 + h)*1024 + pos] = __logf(L);
}

// ================= fallback (R1 mono kernel) if ws too small ==========
#define QT 64
#define KT 64
#define LDP 72
__global__ __launch_bounds__(256, 4)
void zz_fa_mono(const float* __restrict__ Q, const float* __restrict__ K,
                const float* __restrict__ V, float* __restrict__ Out) {
    const int h  = blockIdx.x & 7;
    const int qt = 63 - (blockIdx.x >> 3);
    const int qbase = qt * QT;
    const int tid  = threadIdx.x;
    const int wave = tid >> 6;
    const int lane = tid & 63;
    const int l15  = lane & 15;
    const int quad = lane >> 4;

    __shared__ short Kb[KT][LDP];
    __shared__ short Vt[HD][LDP];
    __shared__ short Pb[4][16][LDP];

    const int qrow = qbase + wave * 16 + l15;
    bf16x8 qf[2];
    {
        const float* qp = Q + ((size_t)qrow * NH + h) * HD + quad * 8;
        #pragma unroll
        for (int cc = 0; cc < 2; ++cc) {
            const float* p = qp + cc * 32;
            float4 a = *(const float4*)p;
            float4 b = *(const float4*)(p + 4);
            bf16x8 f;
            f[0]=f2bf(a.x); f[1]=f2bf(a.y); f[2]=f2bf(a.z); f[3]=f2bf(a.w);
            f[4]=f2bf(b.x); f[5]=f2bf(b.y); f[6]=f2bf(b.z); f[7]=f2bf(b.w);
            qf[cc] = f;
        }
    }
    f32x4 o[4];
    #pragma unroll
    for (int nt = 0; nt < 4; ++nt) o[nt] = (f32x4)0.f;
    float m_i[4] = {-INFINITY, -INFINITY, -INFINITY, -INFINITY};
    float l_i[4] = {0.f, 0.f, 0.f, 0.f};
    const int kkK = tid >> 2, dK = (tid & 3) * 16;
    const int kkV = tid & 63, dV = (tid >> 6) * 16;
    const float scale = 0.125f;

    for (int kt = 0; kt <= qt; ++kt) {
        const int kbase = kt * KT;
        __syncthreads();
        {
            const float* kp = K + ((size_t)(kbase + kkK) * NH + h) * HD + dK;
            #pragma unroll
            for (int i = 0; i < 4; ++i) {
                float4 x = *(const float4*)(kp + i * 4);
                short4v s4;
                s4[0]=f2bf(x.x); s4[1]=f2bf(x.y); s4[2]=f2bf(x.z); s4[3]=f2bf(x.w);
                *(short4v*)&Kb[kkK][dK + i * 4] = s4;
            }
        }
        {
            const float* vp = V + ((size_t)(kbase + kkV) * NH + h) * HD + dV;
            #pragma unroll
            for (int i = 0; i < 4; ++i) {
                float4 x = *(const float4*)(vp + i * 4);
                Vt[dV + i*4 + 0][kkV] = f2bf(x.x);
                Vt[dV + i*4 + 1][kkV] = f2bf(x.y);
                Vt[dV + i*4 + 2][kkV] = f2bf(x.z);
                Vt[dV + i*4 + 3][kkV] = f2bf(x.w);
            }
        }
        __syncthreads();
        f32x4 s[4];
        #pragma unroll
        for (int nt = 0; nt < 4; ++nt) {
            f32x4 acc = (f32x4)0.f;
            #pragma unroll
            for (int kc = 0; kc < 2; ++kc) {
                bf16x8 bf = *(const bf16x8*)&Kb[nt*16 + l15][kc*32 + quad*8];
                acc = __builtin_amdgcn_mfma_f32_16x16x32_bf16(qf[kc], bf, acc, 0, 0, 0);
            }
            s[nt] = acc;
        }
        if (kt == qt) {
            #pragma unroll
            for (int nt = 0; nt < 4; ++nt) {
                const int kj = nt*16 + l15;
                #pragma unroll
                for (int r = 0; r < 4; ++r) {
                    const int qi = wave*16 + quad*4 + r;
                    s[nt][r] = (kj <= qi) ? s[nt][r] * scale : -INFINITY;
                }
            }
        } else {
            #pragma unroll
            for (int nt = 0; nt < 4; ++nt)
                #pragma unroll
                for (int r = 0; r < 4; ++r) s[nt][r] *= scale;
        }
        float alpha[4], lsum[4];
        #pragma unroll
        for (int r = 0; r < 4; ++r) {
            float mx = fmaxf(fmaxf(s[0][r], s[1][r]), fmaxf(s[2][r], s[3][r]));
            #pragma unroll
            for (int msk = 1; msk < 16; msk <<= 1)
                mx = fmaxf(mx, __shfl_xor(mx, msk));
            const float mnew = fmaxf(m_i[r], mx);
            alpha[r] = __expf(m_i[r] - mnew);
            m_i[r] = mnew;
            lsum[r] = 0.f;
        }
        #pragma unroll
        for (int nt = 0; nt < 4; ++nt) {
            #pragma unroll
            for (int r = 0; r < 4; ++r) {
                const float p = __expf(s[nt][r] - m_i[r]);
                lsum[r] += p;
                Pb[wave][quad*4 + r][nt*16 + l15] = f2bf(p);
            }
        }
        #pragma unroll
        for (int r = 0; r < 4; ++r) {
            float ls = lsum[r];
            #pragma unroll
            for (int msk = 1; msk < 16; msk <<= 1)
                ls += __shfl_xor(ls, msk);
            l_i[r] = l_i[r] * alpha[r] + ls;
        }
        #pragma unroll
        for (int nt = 0; nt < 4; ++nt)
            #pragma unroll
            for (int r = 0; r < 4; ++r)
                o[nt][r] *= alpha[r];
        bf16x8 pf[2];
        #pragma unroll
        for (int kc = 0; kc < 2; ++kc)
            pf[kc] = *(const bf16x8*)&Pb[wave][l15][kc*32 + quad*8];
        #pragma unroll
        for (int nt = 0; nt < 4; ++nt) {
            #pragma unroll
            for (int kc = 0; kc < 2; ++kc) {
                bf16x8 vf = *(const bf16x8*)&Vt[nt*16 + l15][kc*32 + quad*8];
                o[nt] = __builtin_amdgcn_mfma_f32_16x16x32_bf16(pf[kc], vf, o[nt], 0, 0, 0);
            }
        }
    }
    #pragma unroll
    for (int r = 0; r < 4; ++r) {
        const int qi   = qbase + wave*16 + quad*4 + r;
        const int g    = qi >> 9;
        const int rank = (g < 4) ? g : (7 - g);
        const int pos  = ((g < 4) ? 0 : 512) + (qi & 511);
        const float inv = 1.f / l_i[r];
        float* ob = Out + ((size_t)(rank * 1024 + pos) * NH + h) * HD;
        #pragma unroll
        for (int nt = 0; nt < 4; ++nt)
            ob[nt*16 + l15] = o[nt][r] * inv;
        if (l15 == 0)
            Out[2097152 + (rank*8 + h)*1024 + pos] = m_i[r] + __logf(l_i[r]);
    }
}

extern "C" void kernel_launch(void* const* d_in, const int* in_sizes, int n_in,
                              void* d_out, int out_size, void* d_ws, size_t ws_size,
                              hipStream_t stream) {
    const float* q = (const float*)d_in[0];
    const float* k = (const float*)d_in[1];
    const float* v = (const float*)d_in[2];
    float* out = (float*)d_out;

    const size_t kbf_elems = (size_t)NH * NKT * 64 * 64;          // 2,097,152 shorts
    const size_t po_elems  = (size_t)NH * MAXC * S_LEN * HD;      // 8,388,608 ushorts
    const size_t ml_elems  = (size_t)NH * MAXC * S_LEN;           // 131,072 floats
    const size_t need = kbf_elems*2*2 + po_elems*2 + ml_elems*4;  // ~25.7 MB

    if (ws_size >= need) {
        short* Kbf = (short*)d_ws;
        short* Vtbf = Kbf + kbf_elems;
        unsigned short* Po = (unsigned short*)(Vtbf + kbf_elems);
        float* Ml = (float*)(Po + po_elems);
        zz_prep<<<dim3(512), dim3(256), 0, stream>>>(k, v, Kbf, Vtbf);
        zz_fa_split<<<dim3(1280), dim3(256), 0, stream>>>(q, Kbf, Vtbf, Po, Ml);
        zz_merge<<<dim3((NH * S_LEN * HD) / 256), dim3(256), 0, stream>>>(Po, Ml, out);
    } else {
        zz_fa_mono<<<dim3(512), dim3(256), 0, stream>>>(q, k, v, out);
    }
}